// Round 6
// baseline (65.542 us; speedup 1.0000x reference)
//
#include <hip/hip_runtime.h>

#define WAVE 64
#define SPB 4   // segments (waves) per block
typedef float v4f __attribute__((ext_vector_type(4)));

// idx may be int32 (JAX default) or int64 (x64 enabled). Detection: odd 32-bit
// words in the upper half are high words of values < 2^31 under int64 layout
// (all zero); under int32 layout they are sorted values ~S/2 (nonzero).
__global__ void detect_idx64(const unsigned int* __restrict__ w32, long long N,
                             int* __restrict__ flag) {
    long long base = (N / 2) | 1LL;
    long long stride = ((N / 2) / 64) & ~1LL;
    if (stride < 2) stride = 2;
    long long p = base + (long long)threadIdx.x * stride;
    unsigned int v = (p < N) ? w32[p] : 0u;
    unsigned long long nz = __ballot(v != 0u);
    if (threadIdx.x == 0) *flag = (nz == 0ULL) ? 1 : 0;   // 1 -> int64
}

__device__ __forceinline__ int load_idx(const void* __restrict__ p,
                                        long long i, int is64) {
    return is64 ? (int)((const long long*)p)[i] : ((const int*)p)[i];
}

// Coalesced pass over idx, 4 elements/thread, vector loads; neighbor's last
// value via __shfl_up (lane 0 of each wave reloads it). start[s]=lower_bound(s).
__global__ void find_bounds(const void* __restrict__ idxp,
                            const int* __restrict__ flag,
                            int* __restrict__ start,
                            long long N, int S) {
    const long long b = ((long long)blockIdx.x * blockDim.x + threadIdx.x) << 2;
    const bool active = b < N;
    const int is64 = *flag;

    int v0 = 0, v1 = 0, v2 = 0, v3 = 0;
    int nval = 0;
    if (active) {
        if (b + 4 <= N) {
            nval = 4;
            if (is64) {
                const longlong2* p = (const longlong2*)((const long long*)idxp + b);
                longlong2 q0 = p[0], q1 = p[1];
                v0 = (int)q0.x; v1 = (int)q0.y; v2 = (int)q1.x; v3 = (int)q1.y;
            } else {
                int4 q = *(const int4*)((const int*)idxp + b);
                v0 = q.x; v1 = q.y; v2 = q.z; v3 = q.w;
            }
        } else {
            nval = (int)(N - b);
            v0 = load_idx(idxp, b, is64);
            if (nval > 1) v1 = load_idx(idxp, b + 1, is64);
            if (nval > 2) v2 = load_idx(idxp, b + 2, is64);
        }
    }
    int last = (nval == 4) ? v3 : (nval == 3) ? v2 : (nval == 2) ? v1 : v0;
    int prev = __shfl_up(last, 1);
    if ((threadIdx.x & 63) == 0)
        prev = (b == 0) ? -1 : (active ? load_idx(idxp, b - 1, is64) : 0);
    if (!active) return;

    int c = prev;
    if (nval >= 1) { if (v0 > c) { for (int t = c + 1; t <= v0; ++t) start[t] = (int)(b);     } c = v0; }
    if (nval >= 2) { if (v1 > c) { for (int t = c + 1; t <= v1; ++t) start[t] = (int)(b + 1); } c = v1; }
    if (nval >= 3) { if (v2 > c) { for (int t = c + 1; t <= v2; ++t) start[t] = (int)(b + 2); } c = v2; }
    if (nval >= 4) { if (v3 > c) { for (int t = c + 1; t <= v3; ++t) start[t] = (int)(b + 3); } c = v3; }
    if (b + nval >= N)
        for (int t = c + 1; t <= S; ++t) start[t] = (int)N;
}

// Persistent: 2048 blocks (8/CU), each wave grid-strides over segments so the
// next iteration's loads issue while the previous iteration's stores drain.
// Per segment: <=2 statically-peeled lane-iterations of float4 loads feed both
// the reduction and (from the same registers) the normalize+store. Bounds via
// readfirstlane -> scalar loads. Iteration B skipped wave-uniformly when empty.
__global__ __launch_bounds__(SPB * WAVE)
void seg_norm(const float* __restrict__ pos,
              const float* __restrict__ w,
              const int* __restrict__ start,
              float* __restrict__ out,
              float* __restrict__ diam_out,
              int S) {
    const int wid  = threadIdx.x >> 6;
    const int lane = threadIdx.x & 63;
    const int step = gridDim.x * SPB;

    const float4* __restrict__ pos4 = (const float4*)pos;
    const float4* __restrict__ w4   = (const float4*)w;
    float4* __restrict__ out4 = (float4*)out;

    for (int s = blockIdx.x * SPB + wid; s < S; s += step) {
        const int su = __builtin_amdgcn_readfirstlane(s);
        const int lo = start[su], hi = start[su + 1];
        const int g0 = lo >> 2, g1 = (hi + 3) >> 2;     // 4-point groups

        const int ga = g0 + lane;
        const int gb = ga + WAVE;
        const bool va = ga < g1, vb = gb < g1;
        const bool anyb = __any(vb);

        float4 a0 = {0,0,0,0}, a1 = {0,0,0,0}, a2 = {0,0,0,0}, aw = {0,0,0,0};
        float4 b0 = {0,0,0,0}, b1 = {0,0,0,0}, b2 = {0,0,0,0}, bw = {0,0,0,0};
        if (va) {
            a0 = pos4[3LL * ga]; a1 = pos4[3LL * ga + 1]; a2 = pos4[3LL * ga + 2];
            aw = w4[ga];
        }
        if (anyb && vb) {
            b0 = pos4[3LL * gb]; b1 = pos4[3LL * gb + 1]; b2 = pos4[3LL * gb + 2];
            bw = w4[gb];
        }

        float mnx = INFINITY,  mny = INFINITY,  mnz = INFINITY;
        float mxx = -INFINITY, mxy = -INFINITY, mxz = -INFINITY;
        float sw = 0.f, swx = 0.f, swy = 0.f, swz = 0.f;

        // p+0: (r0.x,r0.y,r0.z) w.x | p+1: (r0.w,r1.x,r1.y) w.y
        // p+2: (r1.z,r1.w,r2.x) w.z | p+3: (r2.y,r2.z,r2.w) w.w
        #define PROC(PI, X, Y, Z, WV)                                        \
        {                                                                    \
            bool in = ((PI) >= lo) & ((PI) < hi);                            \
            float xv = (X), yv = (Y), zv = (Z);                              \
            float wv = in ? (WV) : 0.f;                                      \
            mnx = fminf(mnx, in ? xv :  INFINITY);                           \
            mxx = fmaxf(mxx, in ? xv : -INFINITY);                           \
            mny = fminf(mny, in ? yv :  INFINITY);                           \
            mxy = fmaxf(mxy, in ? yv : -INFINITY);                           \
            mnz = fminf(mnz, in ? zv :  INFINITY);                           \
            mxz = fmaxf(mxz, in ? zv : -INFINITY);                           \
            sw += wv;                                                        \
            swx = fmaf(wv, xv, swx);                                         \
            swy = fmaf(wv, yv, swy);                                         \
            swz = fmaf(wv, zv, swz);                                         \
        }
        #define PROC_GROUP(G, R0, R1, R2, RW)                                \
        {                                                                    \
            const int p = (G) << 2;                                          \
            PROC(p + 0, R0.x, R0.y, R0.z, RW.x)                              \
            PROC(p + 1, R0.w, R1.x, R1.y, RW.y)                              \
            PROC(p + 2, R1.z, R1.w, R2.x, RW.z)                              \
            PROC(p + 3, R2.y, R2.z, R2.w, RW.w)                              \
        }

        PROC_GROUP(ga, a0, a1, a2, aw)
        if (anyb) PROC_GROUP(gb, b0, b1, b2, bw)

        // Pathological tail (segment > 512 points): never taken for this data.
        for (int g = g0 + 2 * WAVE + lane; g < g1; g += WAVE) {
            float4 c0 = pos4[3LL * g], c1 = pos4[3LL * g + 1], c2 = pos4[3LL * g + 2];
            float4 cw = w4[g];
            PROC_GROUP(g, c0, c1, c2, cw)
        }

        #pragma unroll
        for (int off = 1; off < WAVE; off <<= 1) {
            mnx = fminf(mnx, __shfl_xor(mnx, off));
            mny = fminf(mny, __shfl_xor(mny, off));
            mnz = fminf(mnz, __shfl_xor(mnz, off));
            mxx = fmaxf(mxx, __shfl_xor(mxx, off));
            mxy = fmaxf(mxy, __shfl_xor(mxy, off));
            mxz = fmaxf(mxz, __shfl_xor(mxz, off));
            sw  += __shfl_xor(sw,  off);
            swx += __shfl_xor(swx, off);
            swy += __shfl_xor(swy, off);
            swz += __shfl_xor(swz, off);
        }

        const float diam = fmaxf(mxx - mnx, fmaxf(mxy - mny, mxz - mnz));
        const float wsafe = (sw == 0.f) ? 1.f : sw;
        const float cx = swx / wsafe, cy = swy / wsafe, cz = swz / wsafe;
        const float inv = 1.f / (diam + 0.01f);
        if (lane == 0) diam_out[s] = diam;

        #define STORE_GROUP(G, R0, R1, R2)                                       \
        {                                                                        \
            const int p = (G) << 2;                                              \
            float4 ra, rb, rc;                                                   \
            ra.x = (R0.x - cx) * inv; ra.y = (R0.y - cy) * inv;                  \
            ra.z = (R0.z - cz) * inv; ra.w = (R0.w - cx) * inv;                  \
            rb.x = (R1.x - cy) * inv; rb.y = (R1.y - cz) * inv;                  \
            rb.z = (R1.z - cx) * inv; rb.w = (R1.w - cy) * inv;                  \
            rc.x = (R2.x - cz) * inv; rc.y = (R2.y - cx) * inv;                  \
            rc.z = (R2.z - cy) * inv; rc.w = (R2.w - cz) * inv;                  \
            if (p >= lo && p + 4 <= hi) {                                        \
                __builtin_nontemporal_store(*(const v4f*)&ra, (v4f*)&out4[3LL * (G)]);     \
                __builtin_nontemporal_store(*(const v4f*)&rb, (v4f*)&out4[3LL * (G) + 1]); \
                __builtin_nontemporal_store(*(const v4f*)&rc, (v4f*)&out4[3LL * (G) + 2]); \
            } else {                                                             \
                const long long f = 12LL * (G);                                  \
                if (p + 0 >= lo && p + 0 < hi) {                                 \
                    out[f + 0] = ra.x; out[f + 1]  = ra.y; out[f + 2]  = ra.z;   \
                }                                                                \
                if (p + 1 >= lo && p + 1 < hi) {                                 \
                    out[f + 3] = ra.w; out[f + 4]  = rb.x; out[f + 5]  = rb.y;   \
                }                                                                \
                if (p + 2 >= lo && p + 2 < hi) {                                 \
                    out[f + 6] = rb.z; out[f + 7]  = rb.w; out[f + 8]  = rc.x;   \
                }                                                                \
                if (p + 3 >= lo && p + 3 < hi) {                                 \
                    out[f + 9] = rc.y; out[f + 10] = rc.z; out[f + 11] = rc.w;   \
                }                                                                \
            }                                                                    \
        }

        STORE_GROUP(ga, a0, a1, a2)
        if (anyb) STORE_GROUP(gb, b0, b1, b2)

        // Tail normalize (reload path; never taken for this data).
        for (int g = g0 + 2 * WAVE + lane; g < g1; g += WAVE) {
            float4 c0 = pos4[3LL * g], c1 = pos4[3LL * g + 1], c2 = pos4[3LL * g + 2];
            STORE_GROUP(g, c0, c1, c2)
        }

        #undef STORE_GROUP
        #undef PROC_GROUP
        #undef PROC
    }
}

extern "C" void kernel_launch(void* const* d_in, const int* in_sizes, int n_in,
                              void* d_out, int out_size, void* d_ws, size_t ws_size,
                              hipStream_t stream) {
    const float* pos  = (const float*)d_in[0];
    const void*  idxp = d_in[1];
    const float* w    = (const float*)d_in[2];

    const long long N = (long long)in_sizes[0] / 3;     // 8388608
    const int S = out_size - in_sizes[0];               // 32768

    float* out = (float*)d_out;
    float* diam_out = out + (long long)in_sizes[0];     // tail of d_out

    int* flag  = (int*)d_ws;
    int* start = (int*)((char*)d_ws + 256);

    detect_idx64<<<1, 64, 0, stream>>>((const unsigned int*)idxp, N, flag);

    const long long nt4 = (N + 3) >> 2;
    find_bounds<<<(int)((nt4 + 255) / 256), 256, 0, stream>>>(idxp, flag, start, N, S);

    int sgrid = (S + SPB - 1) / SPB;                    // segment groups
    int grid = sgrid < 2048 ? sgrid : 2048;             // persistent: 8 blocks/CU
    seg_norm<<<grid, SPB * WAVE, 0, stream>>>(pos, w, start, out, diam_out, S);
}

// Round 8
// 59.572 us; speedup vs baseline: 1.1002x; 1.1002x over previous
//
#include <hip/hip_runtime.h>

#define WAVE 64
#define WPB 4    // waves per block; each wave handles segments sA and sA + S/2

// idx may be int32 (JAX default) or int64 (x64 enabled). Detection: odd 32-bit
// words in the upper half are high words of values < 2^31 under int64 layout
// (all zero); under int32 layout they are sorted values ~S/2 (nonzero).
__global__ void detect_idx64(const unsigned int* __restrict__ w32, long long N,
                             int* __restrict__ flag) {
    long long base = (N / 2) | 1LL;
    long long stride = ((N / 2) / 64) & ~1LL;
    if (stride < 2) stride = 2;
    long long p = base + (long long)threadIdx.x * stride;
    unsigned int v = (p < N) ? w32[p] : 0u;
    unsigned long long nz = __ballot(v != 0u);
    if (threadIdx.x == 0) *flag = (nz == 0ULL) ? 1 : 0;   // 1 -> int64
}

__device__ __forceinline__ int load_idx(const void* __restrict__ p,
                                        long long i, int is64) {
    return is64 ? (int)((const long long*)p)[i] : ((const int*)p)[i];
}

// Coalesced pass over idx, 4 elements/thread, vector loads; neighbor's last
// value via __shfl_up (lane 0 of each wave reloads it). start[s]=lower_bound(s).
__global__ void find_bounds(const void* __restrict__ idxp,
                            const int* __restrict__ flag,
                            int* __restrict__ start,
                            long long N, int S) {
    const long long b = ((long long)blockIdx.x * blockDim.x + threadIdx.x) << 2;
    const bool active = b < N;
    const int is64 = *flag;

    int v0 = 0, v1 = 0, v2 = 0, v3 = 0;
    int nval = 0;
    if (active) {
        if (b + 4 <= N) {
            nval = 4;
            if (is64) {
                const longlong2* p = (const longlong2*)((const long long*)idxp + b);
                longlong2 q0 = p[0], q1 = p[1];
                v0 = (int)q0.x; v1 = (int)q0.y; v2 = (int)q1.x; v3 = (int)q1.y;
            } else {
                int4 q = *(const int4*)((const int*)idxp + b);
                v0 = q.x; v1 = q.y; v2 = q.z; v3 = q.w;
            }
        } else {
            nval = (int)(N - b);
            v0 = load_idx(idxp, b, is64);
            if (nval > 1) v1 = load_idx(idxp, b + 1, is64);
            if (nval > 2) v2 = load_idx(idxp, b + 2, is64);
        }
    }
    int last = (nval == 4) ? v3 : (nval == 3) ? v2 : (nval == 2) ? v1 : v0;
    int prev = __shfl_up(last, 1);
    if ((threadIdx.x & 63) == 0)
        prev = (b == 0) ? -1 : (active ? load_idx(idxp, b - 1, is64) : 0);
    if (!active) return;

    int c = prev;
    if (nval >= 1) { if (v0 > c) { for (int t = c + 1; t <= v0; ++t) start[t] = (int)(b);     } c = v0; }
    if (nval >= 2) { if (v1 > c) { for (int t = c + 1; t <= v1; ++t) start[t] = (int)(b + 1); } c = v1; }
    if (nval >= 3) { if (v2 > c) { for (int t = c + 1; t <= v2; ++t) start[t] = (int)(b + 2); } c = v2; }
    if (nval >= 4) { if (v3 > c) { for (int t = c + 1; t <= v3; ++t) start[t] = (int)(b + 3); } c = v3; }
    if (b + nval >= N)
        for (int t = c + 1; t <= S; ++t) start[t] = (int)N;
}

// One wave : TWO INDEPENDENT segments sA and sB = sA + S/2 (no shared bounds,
// no shared groups — each instance is textually the proven single-segment
// path). All 16 float4 loads issue before any dependent use (2x memory-level
// parallelism); both butterfly reductions interleave (20 values/stage);
// normalize+store straight from the loaded registers.
__global__ __launch_bounds__(WPB * WAVE)
void seg_norm(const float* __restrict__ pos,
              const float* __restrict__ w,
              const int* __restrict__ start,
              float* __restrict__ out,
              float* __restrict__ diam_out,
              int S, int H) {
    const int wid  = threadIdx.x >> 6;
    const int lane = threadIdx.x & 63;
    const int sA = blockIdx.x * WPB + wid;
    if (sA >= H) return;
    const int sB = sA + H;
    const bool hasB = sB < S;

    const int loA = start[sA], hiA = start[sA + 1];
    const int loB = hasB ? start[sB] : 0;
    const int hiB = hasB ? start[sB + 1] : 0;

    const float4* __restrict__ pos4 = (const float4*)pos;
    const float4* __restrict__ w4   = (const float4*)w;

    const int g0A = loA >> 2, g1A = (hiA + 3) >> 2;
    const int g0B = loB >> 2, g1B = (hiB + 3) >> 2;
    const int gaA = g0A + lane, gbA = gaA + WAVE;
    const int gaB = g0B + lane, gbB = gaB + WAVE;
    const bool vaA = gaA < g1A, vbA = gbA < g1A;
    const bool vaB = gaB < g1B, vbB = gbB < g1B;

    // ---- all loads issue here, before any dependent use ----
    float4 Aa0 = {0,0,0,0}, Aa1 = {0,0,0,0}, Aa2 = {0,0,0,0}, Aaw = {0,0,0,0};
    float4 Ab0 = {0,0,0,0}, Ab1 = {0,0,0,0}, Ab2 = {0,0,0,0}, Abw = {0,0,0,0};
    float4 Ba0 = {0,0,0,0}, Ba1 = {0,0,0,0}, Ba2 = {0,0,0,0}, Baw = {0,0,0,0};
    float4 Bb0 = {0,0,0,0}, Bb1 = {0,0,0,0}, Bb2 = {0,0,0,0}, Bbw = {0,0,0,0};
    if (vaA) {
        Aa0 = pos4[3LL * gaA]; Aa1 = pos4[3LL * gaA + 1]; Aa2 = pos4[3LL * gaA + 2];
        Aaw = w4[gaA];
    }
    if (vbA) {
        Ab0 = pos4[3LL * gbA]; Ab1 = pos4[3LL * gbA + 1]; Ab2 = pos4[3LL * gbA + 2];
        Abw = w4[gbA];
    }
    if (vaB) {
        Ba0 = pos4[3LL * gaB]; Ba1 = pos4[3LL * gaB + 1]; Ba2 = pos4[3LL * gaB + 2];
        Baw = w4[gaB];
    }
    if (vbB) {
        Bb0 = pos4[3LL * gbB]; Bb1 = pos4[3LL * gbB + 1]; Bb2 = pos4[3LL * gbB + 2];
        Bbw = w4[gbB];
    }

    // ---- accumulators (prefix-named; no runtime indexing -> stays in VGPRs) ----
    #define DECL_ACC(P)                                                      \
        float P##mnx = INFINITY,  P##mny = INFINITY,  P##mnz = INFINITY;     \
        float P##mxx = -INFINITY, P##mxy = -INFINITY, P##mxz = -INFINITY;    \
        float P##sw = 0.f, P##swx = 0.f, P##swy = 0.f, P##swz = 0.f;
    DECL_ACC(A_)
    DECL_ACC(B_)

    // p+0: (r0.x,r0.y,r0.z) w.x | p+1: (r0.w,r1.x,r1.y) w.y
    // p+2: (r1.z,r1.w,r2.x) w.z | p+3: (r2.y,r2.z,r2.w) w.w
    #define PROC(P, PI, LO, HI, X, Y, Z, WV)                                 \
    {                                                                        \
        bool in = ((PI) >= (LO)) & ((PI) < (HI));                            \
        float xv = (X), yv = (Y), zv = (Z);                                  \
        float wv = in ? (WV) : 0.f;                                          \
        P##mnx = fminf(P##mnx, in ? xv :  INFINITY);                         \
        P##mxx = fmaxf(P##mxx, in ? xv : -INFINITY);                         \
        P##mny = fminf(P##mny, in ? yv :  INFINITY);                         \
        P##mxy = fmaxf(P##mxy, in ? yv : -INFINITY);                         \
        P##mnz = fminf(P##mnz, in ? zv :  INFINITY);                         \
        P##mxz = fmaxf(P##mxz, in ? zv : -INFINITY);                         \
        P##sw += wv;                                                         \
        P##swx = fmaf(wv, xv, P##swx);                                       \
        P##swy = fmaf(wv, yv, P##swy);                                       \
        P##swz = fmaf(wv, zv, P##swz);                                       \
    }
    #define PROC_GROUP(P, G, LO, HI, R0, R1, R2, RW)                         \
    {                                                                        \
        const int p_ = (G) << 2;                                             \
        PROC(P, p_ + 0, LO, HI, R0.x, R0.y, R0.z, RW.x)                      \
        PROC(P, p_ + 1, LO, HI, R0.w, R1.x, R1.y, RW.y)                      \
        PROC(P, p_ + 2, LO, HI, R1.z, R1.w, R2.x, RW.z)                      \
        PROC(P, p_ + 3, LO, HI, R2.y, R2.z, R2.w, RW.w)                      \
    }

    PROC_GROUP(A_, gaA, loA, hiA, Aa0, Aa1, Aa2, Aaw)
    PROC_GROUP(A_, gbA, loA, hiA, Ab0, Ab1, Ab2, Abw)
    PROC_GROUP(B_, gaB, loB, hiB, Ba0, Ba1, Ba2, Baw)
    PROC_GROUP(B_, gbB, loB, hiB, Bb0, Bb1, Bb2, Bbw)

    // Pathological tails (segment > 512 points): never taken for this data.
    for (int g = g0A + 2 * WAVE + lane; g < g1A; g += WAVE) {
        float4 c0 = pos4[3LL * g], c1 = pos4[3LL * g + 1], c2 = pos4[3LL * g + 2];
        float4 cw = w4[g];
        PROC_GROUP(A_, g, loA, hiA, c0, c1, c2, cw)
    }
    for (int g = g0B + 2 * WAVE + lane; g < g1B; g += WAVE) {
        float4 c0 = pos4[3LL * g], c1 = pos4[3LL * g + 1], c2 = pos4[3LL * g + 2];
        float4 cw = w4[g];
        PROC_GROUP(B_, g, loB, hiB, c0, c1, c2, cw)
    }

    // ---- interleaved butterfly: 20 independent values per stage ----
    #define RED(P)                                                           \
        P##mnx = fminf(P##mnx, __shfl_xor(P##mnx, off));                     \
        P##mny = fminf(P##mny, __shfl_xor(P##mny, off));                     \
        P##mnz = fminf(P##mnz, __shfl_xor(P##mnz, off));                     \
        P##mxx = fmaxf(P##mxx, __shfl_xor(P##mxx, off));                     \
        P##mxy = fmaxf(P##mxy, __shfl_xor(P##mxy, off));                     \
        P##mxz = fmaxf(P##mxz, __shfl_xor(P##mxz, off));                     \
        P##sw  += __shfl_xor(P##sw,  off);                                   \
        P##swx += __shfl_xor(P##swx, off);                                   \
        P##swy += __shfl_xor(P##swy, off);                                   \
        P##swz += __shfl_xor(P##swz, off);
    #pragma unroll
    for (int off = 1; off < WAVE; off <<= 1) {
        RED(A_)
        RED(B_)
    }
    #undef RED

    // ---- finalize ----
    const float diamA = fmaxf(A_mxx - A_mnx, fmaxf(A_mxy - A_mny, A_mxz - A_mnz));
    const float diamB = fmaxf(B_mxx - B_mnx, fmaxf(B_mxy - B_mny, B_mxz - B_mnz));
    const float wsA = (A_sw == 0.f) ? 1.f : A_sw;
    const float wsB = (B_sw == 0.f) ? 1.f : B_sw;
    const float cxA = A_swx / wsA, cyA = A_swy / wsA, czA = A_swz / wsA;
    const float cxB = B_swx / wsB, cyB = B_swy / wsB, czB = B_swz / wsB;
    const float invA = 1.f / (diamA + 0.01f);
    const float invB = 1.f / (diamB + 0.01f);
    if (lane == 0) {
        diam_out[sA] = diamA;
        if (hasB) diam_out[sB] = diamB;
    }

    // ---- normalize + store from the already-loaded registers ----
    float4* __restrict__ out4 = (float4*)out;
    #define STORE_GROUP(G, LO, HI, CX, CY, CZ, INV, R0, R1, R2)              \
    {                                                                        \
        const int p_ = (G) << 2;                                             \
        float4 ra, rb, rc;                                                   \
        ra.x = (R0.x - (CX)) * (INV); ra.y = (R0.y - (CY)) * (INV);          \
        ra.z = (R0.z - (CZ)) * (INV); ra.w = (R0.w - (CX)) * (INV);          \
        rb.x = (R1.x - (CY)) * (INV); rb.y = (R1.y - (CZ)) * (INV);          \
        rb.z = (R1.z - (CX)) * (INV); rb.w = (R1.w - (CY)) * (INV);          \
        rc.x = (R2.x - (CZ)) * (INV); rc.y = (R2.y - (CX)) * (INV);          \
        rc.z = (R2.z - (CY)) * (INV); rc.w = (R2.w - (CZ)) * (INV);          \
        if (p_ >= (LO) && p_ + 4 <= (HI)) {                                  \
            out4[3LL * (G)] = ra; out4[3LL * (G) + 1] = rb;                  \
            out4[3LL * (G) + 2] = rc;                                        \
        } else {                                                             \
            const long long f = 12LL * (G);                                  \
            if (p_ + 0 >= (LO) && p_ + 0 < (HI)) {                           \
                out[f + 0] = ra.x; out[f + 1]  = ra.y; out[f + 2]  = ra.z;   \
            }                                                                \
            if (p_ + 1 >= (LO) && p_ + 1 < (HI)) {                           \
                out[f + 3] = ra.w; out[f + 4]  = rb.x; out[f + 5]  = rb.y;   \
            }                                                                \
            if (p_ + 2 >= (LO) && p_ + 2 < (HI)) {                           \
                out[f + 6] = rb.z; out[f + 7]  = rb.w; out[f + 8]  = rc.x;   \
            }                                                                \
            if (p_ + 3 >= (LO) && p_ + 3 < (HI)) {                           \
                out[f + 9] = rc.y; out[f + 10] = rc.z; out[f + 11] = rc.w;   \
            }                                                                \
        }                                                                    \
    }

    STORE_GROUP(gaA, loA, hiA, cxA, cyA, czA, invA, Aa0, Aa1, Aa2)
    STORE_GROUP(gbA, loA, hiA, cxA, cyA, czA, invA, Ab0, Ab1, Ab2)
    STORE_GROUP(gaB, loB, hiB, cxB, cyB, czB, invB, Ba0, Ba1, Ba2)
    STORE_GROUP(gbB, loB, hiB, cxB, cyB, czB, invB, Bb0, Bb1, Bb2)

    // Tail stores (reload path; never taken for this data).
    for (int g = g0A + 2 * WAVE + lane; g < g1A; g += WAVE) {
        float4 c0 = pos4[3LL * g], c1 = pos4[3LL * g + 1], c2 = pos4[3LL * g + 2];
        STORE_GROUP(g, loA, hiA, cxA, cyA, czA, invA, c0, c1, c2)
    }
    for (int g = g0B + 2 * WAVE + lane; g < g1B; g += WAVE) {
        float4 c0 = pos4[3LL * g], c1 = pos4[3LL * g + 1], c2 = pos4[3LL * g + 2];
        STORE_GROUP(g, loB, hiB, cxB, cyB, czB, invB, c0, c1, c2)
    }

    #undef STORE_GROUP
    #undef PROC_GROUP
    #undef PROC
    #undef DECL_ACC
}

extern "C" void kernel_launch(void* const* d_in, const int* in_sizes, int n_in,
                              void* d_out, int out_size, void* d_ws, size_t ws_size,
                              hipStream_t stream) {
    const float* pos  = (const float*)d_in[0];
    const void*  idxp = d_in[1];
    const float* w    = (const float*)d_in[2];

    const long long N = (long long)in_sizes[0] / 3;     // 8388608
    const int S = out_size - in_sizes[0];               // 32768

    float* out = (float*)d_out;
    float* diam_out = out + (long long)in_sizes[0];     // tail of d_out

    int* flag  = (int*)d_ws;
    int* start = (int*)((char*)d_ws + 256);

    detect_idx64<<<1, 64, 0, stream>>>((const unsigned int*)idxp, N, flag);

    const long long nt4 = (N + 3) >> 2;
    find_bounds<<<(int)((nt4 + 255) / 256), 256, 0, stream>>>(idxp, flag, start, N, S);

    const int H = (S + 1) / 2;                          // first-half segment count
    seg_norm<<<(H + WPB - 1) / WPB, WPB * WAVE, 0, stream>>>(
        pos, w, start, out, diam_out, S, H);
}

// Round 9
// 56.520 us; speedup vs baseline: 1.1596x; 1.0540x over previous
//
#include <hip/hip_runtime.h>

#define WAVE 64
#define WPB 2    // waves per block (128-thread blocks: finer launch granularity)

// idx may be int32 (JAX default) or int64 (x64 enabled). Detection: odd 32-bit
// words in the upper half are high words of values < 2^31 under int64 layout
// (all zero); under int32 layout they are sorted values ~S/2 (nonzero).
__global__ void detect_idx64(const unsigned int* __restrict__ w32, long long N,
                             int* __restrict__ flag) {
    long long base = (N / 2) | 1LL;
    long long stride = ((N / 2) / 64) & ~1LL;
    if (stride < 2) stride = 2;
    long long p = base + (long long)threadIdx.x * stride;
    unsigned int v = (p < N) ? w32[p] : 0u;
    unsigned long long nz = __ballot(v != 0u);
    if (threadIdx.x == 0) *flag = (nz == 0ULL) ? 1 : 0;   // 1 -> int64
}

__device__ __forceinline__ int load_idx(const void* __restrict__ p,
                                        long long i, int is64) {
    return is64 ? (int)((const long long*)p)[i] : ((const int*)p)[i];
}

// One independent binary search per boundary: start[t] = lower_bound(idx, t).
// 64 independent 23-probe chains per wave; top tree levels are L2/L3-hot.
// Touches ~4 MB of idx lines instead of streaming all 34-67 MB.
__global__ void find_bounds_bs(const void* __restrict__ idxp,
                               const int* __restrict__ flag,
                               int* __restrict__ start,
                               long long N, int S) {
    const int t = blockIdx.x * blockDim.x + threadIdx.x;
    if (t > S) return;
    const int is64 = *flag;
    long long lo = 0, hi = N;
    while (lo < hi) {
        long long mid = (lo + hi) >> 1;
        if (load_idx(idxp, mid, is64) < t) lo = mid + 1; else hi = mid;
    }
    start[t] = (int)lo;
}

// One wave per segment (R5 body, verbatim; best measured). Segment <= 512
// points (<=2 lane-iterations) in the expected data; both iterations peeled
// statically so all 8 float4 loads issue before any dependent use, and the
// SAME registers feed the normalize phase (no second memory round-trip).
__global__ __launch_bounds__(WPB * WAVE)
void seg_norm(const float* __restrict__ pos,
              const float* __restrict__ w,
              const int* __restrict__ start,
              float* __restrict__ out,
              float* __restrict__ diam_out,
              int S) {
    const int s = blockIdx.x * WPB + (threadIdx.x >> 6);
    if (s >= S) return;
    const int lane = threadIdx.x & 63;

    const int lo = start[s], hi = start[s + 1];
    const int g0 = lo >> 2, g1 = (hi + 3) >> 2;       // 4-point groups

    const float4* __restrict__ pos4 = (const float4*)pos;
    const float4* __restrict__ w4   = (const float4*)w;

    const int ga = g0 + lane;          // iteration 0 group
    const int gb = ga + WAVE;          // iteration 1 group
    const bool va = ga < g1, vb = gb < g1;

    float4 a0 = {0,0,0,0}, a1 = {0,0,0,0}, a2 = {0,0,0,0}, aw = {0,0,0,0};
    float4 b0 = {0,0,0,0}, b1 = {0,0,0,0}, b2 = {0,0,0,0}, bw = {0,0,0,0};
    if (va) {
        a0 = pos4[3LL * ga]; a1 = pos4[3LL * ga + 1]; a2 = pos4[3LL * ga + 2];
        aw = w4[ga];
    }
    if (vb) {
        b0 = pos4[3LL * gb]; b1 = pos4[3LL * gb + 1]; b2 = pos4[3LL * gb + 2];
        bw = w4[gb];
    }

    float mnx = INFINITY,  mny = INFINITY,  mnz = INFINITY;
    float mxx = -INFINITY, mxy = -INFINITY, mxz = -INFINITY;
    float sw = 0.f, swx = 0.f, swy = 0.f, swz = 0.f;

    // p+0: (r0.x,r0.y,r0.z) w.x | p+1: (r0.w,r1.x,r1.y) w.y
    // p+2: (r1.z,r1.w,r2.x) w.z | p+3: (r2.y,r2.z,r2.w) w.w
    #define PROC(PI, X, Y, Z, WV)                                        \
    {                                                                    \
        bool in = ((PI) >= lo) & ((PI) < hi);                            \
        float xv = (X), yv = (Y), zv = (Z);                              \
        float wv = in ? (WV) : 0.f;                                      \
        mnx = fminf(mnx, in ? xv :  INFINITY);                           \
        mxx = fmaxf(mxx, in ? xv : -INFINITY);                           \
        mny = fminf(mny, in ? yv :  INFINITY);                           \
        mxy = fmaxf(mxy, in ? yv : -INFINITY);                           \
        mnz = fminf(mnz, in ? zv :  INFINITY);                           \
        mxz = fmaxf(mxz, in ? zv : -INFINITY);                           \
        sw += wv;                                                        \
        swx = fmaf(wv, xv, swx);                                         \
        swy = fmaf(wv, yv, swy);                                         \
        swz = fmaf(wv, zv, swz);                                         \
    }
    #define PROC_GROUP(G, R0, R1, R2, RW)                                \
    {                                                                    \
        const int p = (G) << 2;                                          \
        PROC(p + 0, R0.x, R0.y, R0.z, RW.x)                              \
        PROC(p + 1, R0.w, R1.x, R1.y, RW.y)                              \
        PROC(p + 2, R1.z, R1.w, R2.x, RW.z)                              \
        PROC(p + 3, R2.y, R2.z, R2.w, RW.w)                              \
    }

    PROC_GROUP(ga, a0, a1, a2, aw)
    PROC_GROUP(gb, b0, b1, b2, bw)

    // Pathological tail (segment > 512 points): never taken for this data.
    for (int g = g0 + 2 * WAVE + lane; g < g1; g += WAVE) {
        float4 c0 = pos4[3LL * g], c1 = pos4[3LL * g + 1], c2 = pos4[3LL * g + 2];
        float4 cw = w4[g];
        PROC_GROUP(g, c0, c1, c2, cw)
    }

    #pragma unroll
    for (int off = 1; off < WAVE; off <<= 1) {
        mnx = fminf(mnx, __shfl_xor(mnx, off));
        mny = fminf(mny, __shfl_xor(mny, off));
        mnz = fminf(mnz, __shfl_xor(mnz, off));
        mxx = fmaxf(mxx, __shfl_xor(mxx, off));
        mxy = fmaxf(mxy, __shfl_xor(mxy, off));
        mxz = fmaxf(mxz, __shfl_xor(mxz, off));
        sw  += __shfl_xor(sw,  off);
        swx += __shfl_xor(swx, off);
        swy += __shfl_xor(swy, off);
        swz += __shfl_xor(swz, off);
    }

    const float diam = fmaxf(mxx - mnx, fmaxf(mxy - mny, mxz - mnz));
    const float wsafe = (sw == 0.f) ? 1.f : sw;
    const float cx = swx / wsafe, cy = swy / wsafe, cz = swz / wsafe;
    const float inv = 1.f / (diam + 0.01f);
    if (lane == 0) diam_out[s] = diam;

    float4* __restrict__ out4 = (float4*)out;

    #define STORE_GROUP(G, R0, R1, R2)                                       \
    {                                                                        \
        const int p = (G) << 2;                                              \
        float4 ra, rb, rc;                                                   \
        ra.x = (R0.x - cx) * inv; ra.y = (R0.y - cy) * inv;                  \
        ra.z = (R0.z - cz) * inv; ra.w = (R0.w - cx) * inv;                  \
        rb.x = (R1.x - cy) * inv; rb.y = (R1.y - cz) * inv;                  \
        rb.z = (R1.z - cx) * inv; rb.w = (R1.w - cy) * inv;                  \
        rc.x = (R2.x - cz) * inv; rc.y = (R2.y - cx) * inv;                  \
        rc.z = (R2.z - cy) * inv; rc.w = (R2.w - cz) * inv;                  \
        if (p >= lo && p + 4 <= hi) {                                        \
            out4[3LL * (G)] = ra; out4[3LL * (G) + 1] = rb;                  \
            out4[3LL * (G) + 2] = rc;                                        \
        } else {                                                             \
            const long long f = 12LL * (G);                                  \
            if (p + 0 >= lo && p + 0 < hi) {                                 \
                out[f + 0] = ra.x; out[f + 1]  = ra.y; out[f + 2]  = ra.z;   \
            }                                                                \
            if (p + 1 >= lo && p + 1 < hi) {                                 \
                out[f + 3] = ra.w; out[f + 4]  = rb.x; out[f + 5]  = rb.y;   \
            }                                                                \
            if (p + 2 >= lo && p + 2 < hi) {                                 \
                out[f + 6] = rb.z; out[f + 7]  = rb.w; out[f + 8]  = rc.x;   \
            }                                                                \
            if (p + 3 >= lo && p + 3 < hi) {                                 \
                out[f + 9] = rc.y; out[f + 10] = rc.z; out[f + 11] = rc.w;   \
            }                                                                \
        }                                                                    \
    }

    STORE_GROUP(ga, a0, a1, a2)   // covers all in-range points; inactive
    STORE_GROUP(gb, b0, b1, b2)   // lanes fail every per-point range test

    // Tail normalize (reload path; never taken for this data).
    for (int g = g0 + 2 * WAVE + lane; g < g1; g += WAVE) {
        float4 c0 = pos4[3LL * g], c1 = pos4[3LL * g + 1], c2 = pos4[3LL * g + 2];
        STORE_GROUP(g, c0, c1, c2)
    }

    #undef STORE_GROUP
    #undef PROC_GROUP
    #undef PROC
}

extern "C" void kernel_launch(void* const* d_in, const int* in_sizes, int n_in,
                              void* d_out, int out_size, void* d_ws, size_t ws_size,
                              hipStream_t stream) {
    const float* pos  = (const float*)d_in[0];
    const void*  idxp = d_in[1];
    const float* w    = (const float*)d_in[2];

    const long long N = (long long)in_sizes[0] / 3;     // 8388608
    const int S = out_size - in_sizes[0];               // 32768

    float* out = (float*)d_out;
    float* diam_out = out + (long long)in_sizes[0];     // tail of d_out

    int* flag  = (int*)d_ws;
    int* start = (int*)((char*)d_ws + 256);

    detect_idx64<<<1, 64, 0, stream>>>((const unsigned int*)idxp, N, flag);

    // One thread per boundary (S+1 of them), 64-thread blocks to spread the
    // latency-bound search chains across all CUs.
    find_bounds_bs<<<(S + 1 + 63) / 64, 64, 0, stream>>>(idxp, flag, start, N, S);

    seg_norm<<<(S + WPB - 1) / WPB, WPB * WAVE, 0, stream>>>(
        pos, w, start, out, diam_out, S);
}